// Round 1
// baseline (244.940 us; speedup 1.0000x reference)
//
#include <hip/hip_runtime.h>

// ---------------- types / helpers ----------------
typedef __attribute__((ext_vector_type(4))) float f32x4;
typedef __attribute__((ext_vector_type(8))) __bf16 bf16x8;
typedef __attribute__((ext_vector_type(8))) unsigned short u16x8;

__device__ __forceinline__ unsigned short f2bf(float f) {
    unsigned int u = __float_as_uint(f);
    u += 0x7fffu + ((u >> 16) & 1u);       // RTNE
    return (unsigned short)(u >> 16);
}

__device__ __forceinline__ float softplus_f(float x) {
    float e = __expf(-fabsf(x));
    return fmaxf(x, 0.0f) + __logf(1.0f + e);
}

typedef __attribute__((address_space(3))) void lds_void_t;
typedef __attribute__((address_space(1))) void glb_void_t;

__device__ __forceinline__ void load16_to_lds(const void* g, const void* l) {
    // dest = wave-uniform LDS base + lane*16 (pass lane0's address; HW adds lane*size)
    __builtin_amdgcn_global_load_lds((glb_void_t*)(unsigned long long)g,
                                     (lds_void_t*)(unsigned int)(unsigned long long)l,
                                     16, 0, 0);
}

// ---------------- prologue: build bf16 A = [x | iv | temb(t)]  [2048][384] ----------------
__global__ void build_A(const float* __restrict__ x, const float* __restrict__ iv,
                        const float* __restrict__ temb, unsigned short* __restrict__ Abf) {
    int idx = blockIdx.x * 256 + threadIdx.x;        // one 8-elem chunk
    if (idx >= 2048 * 48) return;
    int m  = idx / 48;
    int kk = (idx % 48) * 8;
    const float* src;
    if      (kk < 256) src = x    + (size_t)m * 256 + kk;
    else if (kk < 320) src = iv   + (size_t)m * 64  + (kk - 256);
    else               src = temb + (size_t)(m & 127) * 64 + (kk - 320);
    float4 f0 = ((const float4*)src)[0];
    float4 f1 = ((const float4*)src)[1];
    u16x8 o;
    o[0] = f2bf(f0.x); o[1] = f2bf(f0.y); o[2] = f2bf(f0.z); o[3] = f2bf(f0.w);
    o[4] = f2bf(f1.x); o[5] = f2bf(f1.y); o[6] = f2bf(f1.z); o[7] = f2bf(f1.w);
    *(u16x8*)(Abf + (size_t)idx * 8) = o;
}

// ---------------- prologue: build bf16 W = [Wa | Wi | Wt]  [16384][384] ----------------
__global__ void build_W(const float* __restrict__ Wa, const float* __restrict__ Wi,
                        const float* __restrict__ Wt, unsigned short* __restrict__ Wbf) {
    int idx = blockIdx.x * 256 + threadIdx.x;
    if (idx >= 16384 * 48) return;
    int j  = idx / 48;
    int kk = (idx % 48) * 8;
    const float* src;
    if      (kk < 256) src = Wa + (size_t)j * 256 + kk;
    else if (kk < 320) src = Wi + (size_t)j * 64 + (kk - 256);
    else               src = Wt + (size_t)j * 64 + (kk - 320);
    float4 f0 = ((const float4*)src)[0];
    float4 f1 = ((const float4*)src)[1];
    u16x8 o;
    o[0] = f2bf(f0.x); o[1] = f2bf(f0.y); o[2] = f2bf(f0.z); o[3] = f2bf(f0.w);
    o[4] = f2bf(f1.x); o[5] = f2bf(f1.y); o[6] = f2bf(f1.z); o[7] = f2bf(f1.w);
    *(u16x8*)(Wbf + (size_t)idx * 8) = o;
}

// ---------------- prologue: tree time-projections tp3[128][4096], tp2[128][1024], tp1[128][256] ----
__global__ void tree_tproj(const float* __restrict__ temb,
                           const float* __restrict__ tW3, const float* __restrict__ tb3,
                           const float* __restrict__ tW2, const float* __restrict__ tb2,
                           const float* __restrict__ tW1, const float* __restrict__ tb1,
                           float* __restrict__ tp3, float* __restrict__ tp2, float* __restrict__ tp1) {
    __shared__ float se[128 * 64];
    for (int i = threadIdx.x; i < 128 * 64; i += 256) se[i] = temb[i];
    __syncthreads();
    int j = blockIdx.x * 64 + (threadIdx.x >> 2);    // 64 j per block; segments are 64-aligned
    const float* W; const float* bias; float* outp; int stride, jl;
    if      (j < 4096) { W = tW3; bias = tb3; outp = tp3; stride = 4096; jl = j; }
    else if (j < 5120) { W = tW2; bias = tb2; outp = tp2; stride = 1024; jl = j - 4096; }
    else               { W = tW1; bias = tb1; outp = tp1; stride = 256;  jl = j - 5120; }
    float4 wreg[16];
    const float4* wrow = (const float4*)(W + (size_t)jl * 64);
    #pragma unroll
    for (int k = 0; k < 16; ++k) wreg[k] = wrow[k];
    float b = bias[jl];
    for (int t = (threadIdx.x & 3); t < 128; t += 4) {
        const float4* e4 = (const float4*)&se[t * 64];
        float a = b;
        #pragma unroll
        for (int k = 0; k < 16; ++k) {
            float4 e = e4[k];
            a += wreg[k].x * e.x + wreg[k].y * e.y + wreg[k].z * e.z + wreg[k].w * e.w;
        }
        outp[(size_t)t * stride + jl] = a;
    }
}

// ---------------- main: fused GEMM (M=2048,N=16384,K=384) + softplus + tree -> out[2048][256] ----
__global__ __launch_bounds__(256, 2)
void fused_gemm_tree(const unsigned short* __restrict__ Abf,
                     const unsigned short* __restrict__ Wbf,
                     const float* __restrict__ ba,
                     const float* __restrict__ tp3, const float* __restrict__ tp2,
                     const float* __restrict__ tp1,
                     const float* __restrict__ w3, const float* __restrict__ w2,
                     const float* __restrict__ w1,
                     float* __restrict__ out) {
    __shared__ unsigned short sA[128 * 32];
    __shared__ unsigned short sB[128 * 32];

    const int tid  = threadIdx.x;
    const int wave = tid >> 6;
    const int lane = tid & 63;
    const int wr = wave >> 1;         // wave row (0..1) -> 64 M-rows
    const int wc = wave & 1;          // wave col (0..1) -> 64 N-cols = one n-group
    const int lane15 = lane & 15;
    const int quad = lane >> 4;

    const int m0 = blockIdx.y * 128;
    const int n0 = blockIdx.x * 128;

    f32x4 acc[4][4];
    const f32x4 zero = {0.0f, 0.0f, 0.0f, 0.0f};
    #pragma unroll
    for (int i = 0; i < 4; ++i)
        #pragma unroll
        for (int j = 0; j < 4; ++j) acc[i][j] = zero;

    const int arow = wr * 64 + lane15;
    const int brow = wc * 64 + lane15;
    const int koff = quad * 8;

    const unsigned short* aBase = Abf + (size_t)m0 * 384;
    const unsigned short* bBase = Wbf + (size_t)n0 * 384;

    for (int k0 = 0; k0 < 384; k0 += 32) {
        __syncthreads();                          // previous iter's ds_reads done
        #pragma unroll
        for (int r = 0; r < 2; ++r) {
            const int chunk = r * 256 + tid;      // flat 16B chunk of the 8KB tile
            const int row   = chunk >> 2;
            const int kk    = k0 + (chunk & 3) * 8;
            load16_to_lds(aBase + (size_t)row * 384 + kk, &sA[(r * 256 + wave * 64) * 8]);
            load16_to_lds(bBase + (size_t)row * 384 + kk, &sB[(r * 256 + wave * 64) * 8]);
        }
        __syncthreads();                          // compiler emits vmcnt(0) drain here

        bf16x8 af[4], bfr[4];
        #pragma unroll
        for (int i = 0; i < 4; ++i) af[i]  = *(const bf16x8*)&sA[(arow + i * 16) * 32 + koff];
        #pragma unroll
        for (int j = 0; j < 4; ++j) bfr[j] = *(const bf16x8*)&sB[(brow + j * 16) * 32 + koff];
        #pragma unroll
        for (int i = 0; i < 4; ++i)
            #pragma unroll
            for (int j = 0; j < 4; ++j)
                acc[i][j] = __builtin_amdgcn_mfma_f32_16x16x32_bf16(af[i], bfr[j], acc[i][j], 0, 0, 0);
    }

    // ---- epilogue: softplus + 4/4/4 tree, all in-register ----
    // col = n0 + wc*64 + j*16 + lane15 ; within n-group: i_dim=j, jj=(lane15>>2), l=lane&3
    const int n  = blockIdx.x * 2 + wc;           // global n in [0,256)
    const int jj = lane15 >> 2;
    const int l  = lane & 3;
    const int colbase = n0 + wc * 64;

    float w3v[4], w2v[4], w1v[4], bav[4];
    #pragma unroll
    for (int j = 0; j < 4; ++j) {
        w3v[j] = w3[((n * 4 + j) * 4 + jj) * 4 + l];
        w2v[j] = w2[(n * 4 + j) * 4 + jj];
        w1v[j] = w1[n * 4 + j];
        bav[j] = ba[colbase + j * 16 + lane15];
    }

    #pragma unroll
    for (int i = 0; i < 4; ++i) {
        #pragma unroll
        for (int r = 0; r < 4; ++r) {
            const int t = wr * 64 + i * 16 + quad * 4 + r;   // row within tile == time step
            float s1 = 0.0f;
            #pragma unroll
            for (int j = 0; j < 4; ++j) {
                float a0 = softplus_f(acc[i][j][r] + bav[j]);        // fanout activation
                float p3 = a0 * w3v[j];
                p3 += __shfl_xor(p3, 1);                             // sum over l
                p3 += __shfl_xor(p3, 2);
                float a3 = softplus_f(p3 + tp3[t * 4096 + (n * 4 + j) * 4 + jj]);
                float p2 = a3 * w2v[j];
                p2 += __shfl_xor(p2, 4);                             // sum over jj
                p2 += __shfl_xor(p2, 8);
                float a2 = softplus_f(p2 + tp2[t * 1024 + n * 4 + j]);
                s1 += a2 * w1v[j];                                   // sum over i_dim
            }
            float o = softplus_f(s1 + tp1[t * 256 + n]);
            if (lane15 == 0) out[(size_t)(blockIdx.y * 128 + t) * 256 + n] = o;
        }
    }
}

// ---------------- launcher ----------------
extern "C" void kernel_launch(void* const* d_in, const int* in_sizes, int n_in,
                              void* d_out, int out_size, void* d_ws, size_t ws_size,
                              hipStream_t stream) {
    const float* x    = (const float*)d_in[0];
    const float* temb = (const float*)d_in[1];
    const float* iv   = (const float*)d_in[2];
    const float* Wa   = (const float*)d_in[3];
    const float* ba   = (const float*)d_in[4];
    const float* Wt   = (const float*)d_in[5];
    const float* Wi   = (const float*)d_in[6];
    const float* w3   = (const float*)d_in[7];
    const float* tW3  = (const float*)d_in[8];
    const float* tb3  = (const float*)d_in[9];
    const float* w2   = (const float*)d_in[10];
    const float* tW2  = (const float*)d_in[11];
    const float* tb2  = (const float*)d_in[12];
    const float* w1   = (const float*)d_in[13];
    const float* tW1  = (const float*)d_in[14];
    const float* tb1  = (const float*)d_in[15];
    float* out = (float*)d_out;

    char* ws = (char*)d_ws;
    unsigned short* Abf = (unsigned short*)(ws);              //  1,572,864 B  [2048][384] bf16
    unsigned short* Wbf = (unsigned short*)(ws + 1572864);    // 12,582,912 B  [16384][384] bf16
    float* tp3 = (float*)(ws + 14155776);                     //  2,097,152 B  [128][4096]
    float* tp2 = (float*)(ws + 16252928);                     //    524,288 B  [128][1024]
    float* tp1 = (float*)(ws + 16777216);                     //    131,072 B  [128][256]

    build_A<<<dim3(384), dim3(256), 0, stream>>>(x, iv, temb, Abf);
    build_W<<<dim3(3072), dim3(256), 0, stream>>>(Wa, Wi, Wt, Wbf);
    tree_tproj<<<dim3(84), dim3(256), 0, stream>>>(temb, tW3, tb3, tW2, tb2, tW1, tb1, tp3, tp2, tp1);
    fused_gemm_tree<<<dim3(128, 16), dim3(256), 0, stream>>>(Abf, Wbf, ba, tp3, tp2, tp1, w3, w2, w1, out);
}

// Round 2
// 230.753 us; speedup vs baseline: 1.0615x; 1.0615x over previous
//
#include <hip/hip_runtime.h>

// ---------------- types / helpers ----------------
typedef __attribute__((ext_vector_type(4))) float f32x4;
typedef __attribute__((ext_vector_type(8))) __bf16 bf16x8;
typedef __attribute__((ext_vector_type(8))) unsigned short u16x8;

__device__ __forceinline__ unsigned short f2bf(float f) {
    unsigned int u = __float_as_uint(f);
    u += 0x7fffu + ((u >> 16) & 1u);       // RTNE
    return (unsigned short)(u >> 16);
}

__device__ __forceinline__ float softplus_f(float x) {
    float e = __expf(-fabsf(x));
    return fmaxf(x, 0.0f) + __logf(1.0f + e);
}

typedef __attribute__((address_space(3))) void lds_void_t;
typedef __attribute__((address_space(1))) void glb_void_t;

__device__ __forceinline__ void load16_to_lds(const void* g, const void* l) {
    // dest = wave-uniform LDS base + lane*16
    __builtin_amdgcn_global_load_lds((glb_void_t*)(unsigned long long)g,
                                     (lds_void_t*)(unsigned int)(unsigned long long)l,
                                     16, 0, 0);
}

// ---------------- merged prologue ----------------
// bx in [0,3456): bf16 repack of A=[x|iv|temb] [2048][384] and W=[Wa|Wi|Wt] [16384][384]
// bx in [3456,3540): tree time-projections, stored TRANSPOSED (t contiguous):
//   tp3T[4096][128], tp2T[1024][128], tp1T[256][128]
__global__ void prep(const float* __restrict__ x, const float* __restrict__ iv,
                     const float* __restrict__ temb,
                     const float* __restrict__ Wa, const float* __restrict__ Wi,
                     const float* __restrict__ Wt,
                     const float* __restrict__ tW3, const float* __restrict__ tb3,
                     const float* __restrict__ tW2, const float* __restrict__ tb2,
                     const float* __restrict__ tW1, const float* __restrict__ tb1,
                     unsigned short* __restrict__ Abf, unsigned short* __restrict__ Wbf,
                     float* __restrict__ tp3T, float* __restrict__ tp2T,
                     float* __restrict__ tp1T) {
    __shared__ float se[128 * 64];
    const int bx = blockIdx.x;
    const int tid = threadIdx.x;
    if (bx < 3456) {
        int idx = bx * 256 + tid;                // 16B chunk id
        const float* src; unsigned short* dst;
        if (idx < 98304) {                       // A: 2048*48 chunks
            int m = idx / 48, kk = (idx % 48) * 8;
            if      (kk < 256) src = x    + (size_t)m * 256 + kk;
            else if (kk < 320) src = iv   + (size_t)m * 64  + (kk - 256);
            else               src = temb + (size_t)(m & 127) * 64 + (kk - 320);
            dst = Abf + (size_t)idx * 8;
        } else {                                 // W: 16384*48 chunks
            int widx = idx - 98304;
            int j = widx / 48, kk = (widx % 48) * 8;
            if      (kk < 256) src = Wa + (size_t)j * 256 + kk;
            else if (kk < 320) src = Wi + (size_t)j * 64 + (kk - 256);
            else               src = Wt + (size_t)j * 64 + (kk - 320);
            dst = Wbf + (size_t)widx * 8;
        }
        float4 f0 = ((const float4*)src)[0];
        float4 f1 = ((const float4*)src)[1];
        u16x8 o;
        o[0] = f2bf(f0.x); o[1] = f2bf(f0.y); o[2] = f2bf(f0.z); o[3] = f2bf(f0.w);
        o[4] = f2bf(f1.x); o[5] = f2bf(f1.y); o[6] = f2bf(f1.z); o[7] = f2bf(f1.w);
        *(u16x8*)dst = o;
    } else {
        for (int i = tid; i < 128 * 64; i += 256) se[i] = temb[i];
        __syncthreads();
        int j = (bx - 3456) * 64 + (tid >> 2);   // 64 j per block, segments 64-aligned
        const float* W; const float* bias; float* outp; int jl;
        if      (j < 4096) { W = tW3; bias = tb3; outp = tp3T; jl = j; }
        else if (j < 5120) { W = tW2; bias = tb2; outp = tp2T; jl = j - 4096; }
        else               { W = tW1; bias = tb1; outp = tp1T; jl = j - 5120; }
        float4 wreg[16];
        const float4* wrow = (const float4*)(W + (size_t)jl * 64);
        #pragma unroll
        for (int k = 0; k < 16; ++k) wreg[k] = wrow[k];
        float b = bias[jl];
        for (int t = (tid & 3); t < 128; t += 4) {
            const float4* e4 = (const float4*)&se[t * 64];
            float a = b;
            #pragma unroll
            for (int k = 0; k < 16; ++k) {
                float4 e = e4[k];
                a += wreg[k].x * e.x + wreg[k].y * e.y + wreg[k].z * e.z + wreg[k].w * e.w;
            }
            outp[(size_t)jl * 128 + t] = a;      // transposed: t contiguous
        }
    }
}

// ---------------- main: transposed GEMM (M=16384 nodes, N=2048 bt, K=384) + tree ----------------
// C[node][m]: per wave, 64 M-rows = the 64 leaves of ONE n; leaf = i*16 + quad*4 + r
// -> i_dim = i (frag), jj = quad, l = r (in-register!)
__global__ __launch_bounds__(256, 4)
void fused_gemm_tree(const unsigned short* __restrict__ Wbf,   // A-operand [16384][384]
                     const unsigned short* __restrict__ Abf,   // B-operand [2048][384]
                     const float* __restrict__ ba,
                     const float* __restrict__ tp3T, const float* __restrict__ tp2T,
                     const float* __restrict__ tp1T,
                     const float* __restrict__ w3, const float* __restrict__ w2,
                     const float* __restrict__ w1,
                     float* __restrict__ out) {
    __shared__ unsigned short sW[128 * 32];
    __shared__ unsigned short sA[128 * 32];

    const int tid  = threadIdx.x;
    const int wave = tid >> 6;
    const int lane = tid & 63;
    const int wr = wave >> 1;          // node half: n = blockIdx.x*2 + wr
    const int wc = wave & 1;           // time half: 64 m-cols
    const int lane15 = lane & 15;
    const int quad = lane >> 4;

    const int node0 = blockIdx.x * 128;
    const int m0    = blockIdx.y * 128;

    f32x4 acc[4][4];
    const f32x4 zero = {0.0f, 0.0f, 0.0f, 0.0f};
    #pragma unroll
    for (int i = 0; i < 4; ++i)
        #pragma unroll
        for (int j = 0; j < 4; ++j) acc[i][j] = zero;

    const int wrow = wr * 64 + lane15;     // A-side (node) frag row
    const int arow = wc * 64 + lane15;     // B-side (time) frag row
    const int koff = quad * 8;

    const unsigned short* aBase = Wbf + (size_t)node0 * 384;
    const unsigned short* bBase = Abf + (size_t)m0 * 384;

    for (int k0 = 0; k0 < 384; k0 += 32) {
        __syncthreads();
        #pragma unroll
        for (int r = 0; r < 2; ++r) {
            const int chunk = r * 256 + tid;
            const int row   = chunk >> 2;
            const int kk    = k0 + (chunk & 3) * 8;
            load16_to_lds(aBase + (size_t)row * 384 + kk, &sW[(r * 256 + wave * 64) * 8]);
            load16_to_lds(bBase + (size_t)row * 384 + kk, &sA[(r * 256 + wave * 64) * 8]);
        }
        __syncthreads();

        bf16x8 af[4], bfr[4];
        #pragma unroll
        for (int i = 0; i < 4; ++i) af[i]  = *(const bf16x8*)&sW[(wrow + i * 16) * 32 + koff];
        #pragma unroll
        for (int j = 0; j < 4; ++j) bfr[j] = *(const bf16x8*)&sA[(arow + j * 16) * 32 + koff];
        #pragma unroll
        for (int i = 0; i < 4; ++i)
            #pragma unroll
            for (int j = 0; j < 4; ++j)
                acc[i][j] = __builtin_amdgcn_mfma_f32_16x16x32_bf16(af[i], bfr[j], acc[i][j], 0, 0, 0);
    }

    // ---- epilogue: softplus + 4/4/4 tree; l in-register, jj across quads, i in frags ----
    const int n = blockIdx.x * 2 + wr;

    float bav[4][4], w3v[4][4], w2v[4], w1v[4];
    #pragma unroll
    for (int i = 0; i < 4; ++i) {
        #pragma unroll
        for (int r = 0; r < 4; ++r) {
            const int nl = i * 16 + quad * 4 + r;          // leaf within n
            bav[i][r] = ba[node0 + wr * 64 + nl];
            w3v[i][r] = w3[n * 64 + nl];                   // [N,4,4,4] flat
        }
        w2v[i] = w2[n * 16 + i * 4 + quad];                // [N,4,4] flat
        w1v[i] = w1[n * 4 + i];                            // [N,4] flat
    }

    const int tbase = wc * 64 + lane15;                    // + j*16 -> t in [0,128)
    float s1[4] = {0.0f, 0.0f, 0.0f, 0.0f};

    #pragma unroll
    for (int i = 0; i < 4; ++i) {
        const float* tp3row = tp3T + (size_t)(n * 16 + i * 4 + quad) * 128;
        const float* tp2row = tp2T + (size_t)(n * 4 + i) * 128;
        #pragma unroll
        for (int j = 0; j < 4; ++j) {
            const int t = tbase + j * 16;
            float p3 = 0.0f;
            #pragma unroll
            for (int r = 0; r < 4; ++r) {
                float a0 = softplus_f(acc[i][j][r] + bav[i][r]);   // fanout act (once)
                p3 = fmaf(a0, w3v[i][r], p3);                      // sum over l in-register
            }
            float a3 = softplus_f(p3 + tp3row[t]);                 // once per (t,n,i,jj)
            float c2 = a3 * w2v[i];
            c2 += __shfl_xor(c2, 16);                              // sum over jj (quads)
            c2 += __shfl_xor(c2, 32);
            float a2 = softplus_f(c2 + tp2row[t]);
            s1[j] = fmaf(a2, w1v[i], s1[j]);                       // sum over i in-register
        }
    }
    #pragma unroll
    for (int j = 0; j < 4; ++j) {
        const int t = tbase + j * 16;
        float o = softplus_f(s1[j] + tp1T[(size_t)n * 128 + t]);
        if (quad == 0) out[(size_t)(m0 + t) * 256 + n] = o;
    }
}

// ---------------- launcher ----------------
extern "C" void kernel_launch(void* const* d_in, const int* in_sizes, int n_in,
                              void* d_out, int out_size, void* d_ws, size_t ws_size,
                              hipStream_t stream) {
    const float* x    = (const float*)d_in[0];
    const float* temb = (const float*)d_in[1];
    const float* iv   = (const float*)d_in[2];
    const float* Wa   = (const float*)d_in[3];
    const float* ba   = (const float*)d_in[4];
    const float* Wt   = (const float*)d_in[5];
    const float* Wi   = (const float*)d_in[6];
    const float* w3   = (const float*)d_in[7];
    const float* tW3  = (const float*)d_in[8];
    const float* tb3  = (const float*)d_in[9];
    const float* w2   = (const float*)d_in[10];
    const float* tW2  = (const float*)d_in[11];
    const float* tb2  = (const float*)d_in[12];
    const float* w1   = (const float*)d_in[13];
    const float* tW1  = (const float*)d_in[14];
    const float* tb1  = (const float*)d_in[15];
    float* out = (float*)d_out;

    char* ws = (char*)d_ws;
    unsigned short* Abf = (unsigned short*)(ws);              //  1,572,864 B  [2048][384] bf16
    unsigned short* Wbf = (unsigned short*)(ws + 1572864);    // 12,582,912 B  [16384][384] bf16
    float* tp3T = (float*)(ws + 14155776);                    //  2,097,152 B  [4096][128]
    float* tp2T = (float*)(ws + 16252928);                    //    524,288 B  [1024][128]
    float* tp1T = (float*)(ws + 16777216);                    //    131,072 B  [256][128]

    prep<<<dim3(3540), dim3(256), 0, stream>>>(x, iv, temb, Wa, Wi, Wt,
                                               tW3, tb3, tW2, tb2, tW1, tb1,
                                               Abf, Wbf, tp3T, tp2T, tp1T);
    fused_gemm_tree<<<dim3(128, 16), dim3(256), 0, stream>>>(Wbf, Abf, ba, tp3T, tp2T, tp1T,
                                                             w3, w2, w1, out);
}

// Round 3
// 161.996 us; speedup vs baseline: 1.5120x; 1.4244x over previous
//
#include <hip/hip_runtime.h>

// ---------------- types / helpers ----------------
typedef __attribute__((ext_vector_type(4))) float f32x4;
typedef __attribute__((ext_vector_type(8))) __bf16 bf16x8;
typedef __attribute__((ext_vector_type(8))) unsigned short u16x8;

__device__ __forceinline__ unsigned short f2bf(float f) {
    unsigned int u = __float_as_uint(f);
    u += 0x7fffu + ((u >> 16) & 1u);       // RTNE
    return (unsigned short)(u >> 16);
}

__device__ __forceinline__ float softplus_f(float x) {
    float e = __expf(-fabsf(x));
    return fmaxf(x, 0.0f) + __logf(1.0f + e);
}

typedef __attribute__((address_space(3))) void lds_void_t;
typedef __attribute__((address_space(1))) void glb_void_t;

__device__ __forceinline__ void load16_to_lds(const void* g, const void* l) {
    __builtin_amdgcn_global_load_lds((glb_void_t*)(unsigned long long)g,
                                     (lds_void_t*)(unsigned int)(unsigned long long)l,
                                     16, 0, 0);
}

// ---------------- repack: bf16 A=[x|iv|temb] then W=[Wa|Wi|Wt], dst contiguous ----------------
// 884736 chunks of 8 elems: idx<98304 -> A [2048][384]; else W [16384][384].
// Batched grid-stride: NB=4 chunks/thread, all 8 float4 loads in flight before converts.
#define REPACK_NB 4
#define REPACK_BLOCKS 864
__global__ __launch_bounds__(256) void repack(
        const float* __restrict__ x, const float* __restrict__ iv,
        const float* __restrict__ temb,
        const float* __restrict__ Wa, const float* __restrict__ Wi,
        const float* __restrict__ Wt,
        unsigned short* __restrict__ Abf /* Wbf follows contiguously */) {
    const int stride = REPACK_BLOCKS * 256;
    const int tid0 = blockIdx.x * 256 + threadIdx.x;
    float4 f[REPACK_NB][2];
    #pragma unroll
    for (int c = 0; c < REPACK_NB; ++c) {
        const int idx = tid0 + c * stride;
        const bool isA = idx < 98304;
        const int widx = isA ? idx : idx - 98304;
        const int row = widx / 48;
        const int kk  = (widx % 48) * 8;
        // branchless 3-way source select (cndmask on pointers, no divergence)
        const float* p0 = isA ? (x    + (size_t)row * 256) : (Wa + (size_t)row * 256);
        const float* p1 = isA ? (iv   + (size_t)row * 64)  : (Wi + (size_t)row * 64);
        const float* p2 = isA ? (temb + (size_t)(row & 127) * 64) : (Wt + (size_t)row * 64);
        const float* src = (kk < 256) ? (p0 + kk) : ((kk < 320) ? (p1 + kk - 256) : (p2 + kk - 320));
        f[c][0] = ((const float4*)src)[0];
        f[c][1] = ((const float4*)src)[1];
    }
    #pragma unroll
    for (int c = 0; c < REPACK_NB; ++c) {
        const int idx = tid0 + c * stride;
        u16x8 o;
        o[0] = f2bf(f[c][0].x); o[1] = f2bf(f[c][0].y); o[2] = f2bf(f[c][0].z); o[3] = f2bf(f[c][0].w);
        o[4] = f2bf(f[c][1].x); o[5] = f2bf(f[c][1].y); o[6] = f2bf(f[c][1].z); o[7] = f2bf(f[c][1].w);
        *(u16x8*)(Abf + (size_t)idx * 8) = o;   // Abf/Wbf contiguous: uniform dst
    }
}

// ---------------- tproj: tp3T[4096][128], tp2T[1024][128], tp1T[256][128] (t contiguous) ----
// grid (84, 4): 64 j per block, 32 t per by-slice.
__global__ __launch_bounds__(256) void tproj(
        const float* __restrict__ temb,
        const float* __restrict__ tW3, const float* __restrict__ tb3,
        const float* __restrict__ tW2, const float* __restrict__ tb2,
        const float* __restrict__ tW1, const float* __restrict__ tb1,
        float* __restrict__ tp3T, float* __restrict__ tp2T, float* __restrict__ tp1T) {
    __shared__ float se[32 * 64];
    const int tid = threadIdx.x;
    const int tbase = blockIdx.y * 32;
    for (int i = tid; i < 32 * 64; i += 256) se[i] = temb[tbase * 64 + i];
    __syncthreads();
    const int j = blockIdx.x * 64 + (tid >> 2);      // segments 64-aligned
    const float* W; const float* bias; float* outp; int jl;
    if      (j < 4096) { W = tW3; bias = tb3; outp = tp3T; jl = j; }
    else if (j < 5120) { W = tW2; bias = tb2; outp = tp2T; jl = j - 4096; }
    else               { W = tW1; bias = tb1; outp = tp1T; jl = j - 5120; }
    float4 wreg[16];
    const float4* wrow = (const float4*)(W + (size_t)jl * 64);
    #pragma unroll
    for (int k = 0; k < 16; ++k) wreg[k] = wrow[k];
    const float b = bias[jl];
    #pragma unroll
    for (int s = 0; s < 8; ++s) {
        const int tl = (tid & 3) + s * 4;
        const float4* e4 = (const float4*)&se[tl * 64];
        float a = b;
        #pragma unroll
        for (int k = 0; k < 16; ++k) {
            float4 e = e4[k];
            a += wreg[k].x * e.x + wreg[k].y * e.y + wreg[k].z * e.z + wreg[k].w * e.w;
        }
        outp[(size_t)jl * 128 + tbase + tl] = a;
    }
}

// ---------------- main: transposed GEMM (M=16384 nodes, N=2048 bt, K=384) + tree ----------------
// C[node][m]: per wave, 64 M-rows = the 64 leaves of ONE n; leaf = i*16 + quad*4 + r
// -> i_dim = i (frag), jj = quad, l = r (in-register)
__global__ __launch_bounds__(256, 4)
void fused_gemm_tree(const unsigned short* __restrict__ Wbf,   // A-operand [16384][384]
                     const unsigned short* __restrict__ Abf,   // B-operand [2048][384]
                     const float* __restrict__ ba,
                     const float* __restrict__ tp3T, const float* __restrict__ tp2T,
                     const float* __restrict__ tp1T,
                     const float* __restrict__ w3, const float* __restrict__ w2,
                     const float* __restrict__ w1,
                     float* __restrict__ out) {
    __shared__ unsigned short sW[128 * 32];
    __shared__ unsigned short sA[128 * 32];

    const int tid  = threadIdx.x;
    const int wave = tid >> 6;
    const int lane = tid & 63;
    const int wr = wave >> 1;          // node half: n = blockIdx.x*2 + wr
    const int wc = wave & 1;           // time half: 64 m-cols
    const int lane15 = lane & 15;
    const int quad = lane >> 4;

    const int node0 = blockIdx.x * 128;
    const int m0    = blockIdx.y * 128;

    f32x4 acc[4][4];
    const f32x4 zero = {0.0f, 0.0f, 0.0f, 0.0f};
    #pragma unroll
    for (int i = 0; i < 4; ++i)
        #pragma unroll
        for (int j = 0; j < 4; ++j) acc[i][j] = zero;

    const int wrow = wr * 64 + lane15;     // A-side (node) frag row
    const int arow = wc * 64 + lane15;     // B-side (time) frag row
    const int koff = quad * 8;

    const unsigned short* aBase = Wbf + (size_t)node0 * 384;
    const unsigned short* bBase = Abf + (size_t)m0 * 384;

    for (int k0 = 0; k0 < 384; k0 += 32) {
        __syncthreads();
        #pragma unroll
        for (int r = 0; r < 2; ++r) {
            const int chunk = r * 256 + tid;
            const int row   = chunk >> 2;
            const int kk    = k0 + (chunk & 3) * 8;
            load16_to_lds(aBase + (size_t)row * 384 + kk, &sW[(r * 256 + wave * 64) * 8]);
            load16_to_lds(bBase + (size_t)row * 384 + kk, &sA[(r * 256 + wave * 64) * 8]);
        }
        __syncthreads();

        bf16x8 af[4], bfr[4];
        #pragma unroll
        for (int i = 0; i < 4; ++i) af[i]  = *(const bf16x8*)&sW[(wrow + i * 16) * 32 + koff];
        #pragma unroll
        for (int j = 0; j < 4; ++j) bfr[j] = *(const bf16x8*)&sA[(arow + j * 16) * 32 + koff];
        #pragma unroll
        for (int i = 0; i < 4; ++i)
            #pragma unroll
            for (int j = 0; j < 4; ++j)
                acc[i][j] = __builtin_amdgcn_mfma_f32_16x16x32_bf16(af[i], bfr[j], acc[i][j], 0, 0, 0);
    }

    // ---- epilogue: softplus + 4/4/4 tree; l in-register, jj across quads, i in frags ----
    const int n = blockIdx.x * 2 + wr;

    float bav[4][4], w3v[4][4], w2v[4], w1v[4];
    #pragma unroll
    for (int i = 0; i < 4; ++i) {
        #pragma unroll
        for (int r = 0; r < 4; ++r) {
            const int nl = i * 16 + quad * 4 + r;          // leaf within n
            bav[i][r] = ba[node0 + wr * 64 + nl];
            w3v[i][r] = w3[n * 64 + nl];                   // [N,4,4,4] flat
        }
        w2v[i] = w2[n * 16 + i * 4 + quad];                // [N,4,4] flat
        w1v[i] = w1[n * 4 + i];                            // [N,4] flat
    }

    const int tbase = wc * 64 + lane15;                    // + j*16 -> t in [0,128)
    float s1[4] = {0.0f, 0.0f, 0.0f, 0.0f};

    #pragma unroll
    for (int i = 0; i < 4; ++i) {
        const float* tp3row = tp3T + (size_t)(n * 16 + i * 4 + quad) * 128;
        const float* tp2row = tp2T + (size_t)(n * 4 + i) * 128;
        #pragma unroll
        for (int j = 0; j < 4; ++j) {
            const int t = tbase + j * 16;
            float p3 = 0.0f;
            #pragma unroll
            for (int r = 0; r < 4; ++r) {
                float a0 = softplus_f(acc[i][j][r] + bav[i][r]);   // fanout act (once)
                p3 = fmaf(a0, w3v[i][r], p3);                      // sum over l in-register
            }
            float a3 = softplus_f(p3 + tp3row[t]);                 // once per (t,n,i,jj)
            float c2 = a3 * w2v[i];
            c2 += __shfl_xor(c2, 16);                              // sum over jj (quads)
            c2 += __shfl_xor(c2, 32);
            float a2 = softplus_f(c2 + tp2row[t]);
            s1[j] = fmaf(a2, w1v[i], s1[j]);                       // sum over i in-register
        }
    }
    #pragma unroll
    for (int j = 0; j < 4; ++j) {
        const int t = tbase + j * 16;
        float o = softplus_f(s1[j] + tp1T[(size_t)n * 128 + t]);
        if (quad == 0) out[(size_t)(m0 + t) * 256 + n] = o;
    }
}

// ---------------- launcher ----------------
extern "C" void kernel_launch(void* const* d_in, const int* in_sizes, int n_in,
                              void* d_out, int out_size, void* d_ws, size_t ws_size,
                              hipStream_t stream) {
    const float* x    = (const float*)d_in[0];
    const float* temb = (const float*)d_in[1];
    const float* iv   = (const float*)d_in[2];
    const float* Wa   = (const float*)d_in[3];
    const float* ba   = (const float*)d_in[4];
    const float* Wt   = (const float*)d_in[5];
    const float* Wi   = (const float*)d_in[6];
    const float* w3   = (const float*)d_in[7];
    const float* tW3  = (const float*)d_in[8];
    const float* tb3  = (const float*)d_in[9];
    const float* w2   = (const float*)d_in[10];
    const float* tW2  = (const float*)d_in[11];
    const float* tb2  = (const float*)d_in[12];
    const float* w1   = (const float*)d_in[13];
    const float* tW1  = (const float*)d_in[14];
    const float* tb1  = (const float*)d_in[15];
    float* out = (float*)d_out;

    char* ws = (char*)d_ws;
    unsigned short* Abf = (unsigned short*)(ws);              //  1,572,864 B  [2048][384] bf16
    unsigned short* Wbf = (unsigned short*)(ws + 1572864);    // 12,582,912 B  [16384][384] bf16 (contiguous after Abf)
    float* tp3T = (float*)(ws + 14155776);                    //  2,097,152 B  [4096][128]
    float* tp2T = (float*)(ws + 16252928);                    //    524,288 B  [1024][128]
    float* tp1T = (float*)(ws + 16777216);                    //    131,072 B  [256][128]

    repack<<<dim3(REPACK_BLOCKS), dim3(256), 0, stream>>>(x, iv, temb, Wa, Wi, Wt, Abf);
    tproj<<<dim3(84, 4), dim3(256), 0, stream>>>(temb, tW3, tb3, tW2, tb2, tW1, tb1,
                                                 tp3T, tp2T, tp1T);
    fused_gemm_tree<<<dim3(128, 16), dim3(256), 0, stream>>>(Wbf, Abf, ba, tp3T, tp2T, tp1T,
                                                             w3, w2, w1, out);
}